// Round 6
// baseline (8551.167 us; speedup 1.0000x reference)
//
#include <hip/hip_runtime.h>

#define NN 24576
#define DD 32
#define KK 17
#define PP 20
#define RS 20                       // padded W row stride (floats), 80 B = b128-aligned
#define SLICE (KK * RS)             // 340 floats per (d,p) slice
#define SLICE_F4 (SLICE / 4)        // 85 float4
#define WE ((DD - 1) * PP * SLICE)  // padded W elems per chain

__device__ __forceinline__ float binom16(int k) {
    const float b[KK] = {1.f, 16.f, 120.f, 560.f, 1820.f, 4368.f, 8008.f, 11440.f,
                         12870.f, 11440.f, 8008.f, 4368.f, 1820.f, 560.f, 120.f, 16.f, 1.f};
    return b[k];
}

// t[k] = x^k * (1-x)^(16-k)   (binom folded into weights by prep_w)
__device__ __forceinline__ void bernT(float x, float* t) {
    const float y = 1.0f - x;
    t[0] = 1.0f;
#pragma unroll
    for (int k = 1; k < KK; ++k) t[k] = t[k - 1] * x;
    float yp = y;
#pragma unroll
    for (int k = KK - 2; k >= 0; --k) {
        t[k] *= yp;
        yp *= y;
    }
}

// Padded, binom-folded weight tables (proven in round 4 — correctness passed):
//  Wm[d,p,k,j20] = meanw[d,p,k,j] * binom[j]
//  Wv[d,p,k,j20] = exp(varw[d,p,k,j]) * (sc[j]*binom[j])^2
//  w0m[p,k] = meanw0[p,0,k] * binom[k];  w0v[p,k] = exp(varw0[p,0,k]) * (sc[k]*binom[k])^2
__global__ void prep_w(const float* __restrict__ mw, const float* __restrict__ vw,
                       const float* __restrict__ mw0, const float* __restrict__ vw0,
                       const float* __restrict__ psc,
                       float* __restrict__ Wm, float* __restrict__ Wv,
                       float* __restrict__ w0m, float* __restrict__ w0v) {
    int idx = blockIdx.x * blockDim.x + threadIdx.x;
    if (idx < WE) {
        const int j = idx % RS;
        const int k = (idx / RS) % KK;
        const int p = (idx / SLICE) % PP;
        const int dm1 = idx / (SLICE * PP);
        float v = 0.0f;
        if (j < KK)
            v = mw[(((size_t)dm1 * PP + p) * KK + k) * KK + j] * binom16(j);
        Wm[idx] = v;
    } else if (idx < 2 * WE) {
        const int i = idx - WE;
        const int j = i % RS;
        const int k = (i / RS) % KK;
        const int p = (i / SLICE) % PP;
        const int dm1 = i / (SLICE * PP);
        float v = 0.0f;
        if (j < KK) {
            const float s = psc[j] * binom16(j);
            v = expf(vw[(((size_t)dm1 * PP + p) * KK + k) * KK + j]) * s * s;
        }
        Wv[i] = v;
    } else if (idx < 2 * WE + PP * KK) {
        const int i = idx - 2 * WE;
        const int k = i % KK;
        w0m[i] = mw0[i] * binom16(k);
    } else if (idx < 2 * WE + 2 * PP * KK) {
        const int i = idx - 2 * WE - PP * KK;
        const int k = i % KK;
        const float s = psc[k] * binom16(k);
        w0v[i] = expf(vw0[i]) * s * s;
    }
}

// Transpose X [N,D] -> XT [D,N] so chain-kernel loads are lane-coalesced.
__global__ void transpose_x(const float* __restrict__ X, float* __restrict__ XT) {
    __shared__ float t[32][33];
    const int n0 = blockIdx.x * 32;
    for (int r = threadIdx.y; r < 32; r += 8)
        t[r][threadIdx.x] = X[(n0 + r) * DD + threadIdx.x];
    __syncthreads();
    for (int d = threadIdx.y; d < 32; d += 8)
        XT[d * NN + n0 + threadIdx.x] = t[threadIdx.x][d];
}

// W staged in LDS (4 phases x 8 d-slices), PLAIN scalar compute body
// (round-2's proven loop shape — no manual float4 tiles, no tight bounds).
// Uniform-address ds_reads broadcast (no conflicts); compiler merges the
// j-consecutive reads into aligned ds_read_b128 (rows padded to 80 B).
__global__ __launch_bounds__(256, 4) void bez_chainS(
    const float* __restrict__ Xb,        // XT [DD,NN]
    const float* __restrict__ w0m, const float* __restrict__ w0v,
    const float* __restrict__ Wm,  const float* __restrict__ Wv,  // padded [31,PP,17,20]
    const float* __restrict__ post_prec, const int* __restrict__ perm,
    float* __restrict__ out)
{
    __shared__ __align__(16) float Wlds[8 * SLICE];   // 10,880 B

    const bool VAR = (blockIdx.z != 0);
    const int p = blockIdx.y;
    const int n = blockIdx.x * blockDim.x + threadIdx.x;
    const int tid = threadIdx.x;
    const int* __restrict__ pp = perm + p * DD;
    const float4* __restrict__ Wsrc = (const float4*)(VAR ? Wv : Wm);

    float f[KK], t[KK];

    {   // d = 0
        const float x = Xb[pp[0] * NN + n];
        bernT(x, t);
        if (VAR) {
#pragma unroll
            for (int k = 0; k < KK; ++k) t[k] *= t[k];
        }
        const float* __restrict__ w0 = (VAR ? w0v : w0m) + p * KK;
#pragma unroll
        for (int k = 0; k < KK; ++k) f[k] = w0[k] * t[k];
    }

    int d = 1;
#pragma unroll 1
    for (int phase = 0; phase < 4; ++phase) {
        const int nsl = (phase < 3) ? 8 : 7;

        __syncthreads();   // all waves done reading previous phase
        {
            float4* __restrict__ dst = (float4*)Wlds;
            const float4* __restrict__ src = Wsrc + ((size_t)(d - 1) * PP + p) * SLICE_F4;
            const int tot = nsl * SLICE_F4;
            for (int i = tid; i < tot; i += 256) {
                const int dd = i / SLICE_F4;
                const int r  = i - dd * SLICE_F4;
                dst[i] = src[(size_t)dd * (PP * SLICE_F4) + r];
            }
        }
        __syncthreads();

#pragma unroll 1
        for (int dd = 0; dd < nsl; ++dd, ++d) {
            const float x = Xb[pp[d] * NN + n];      // issue early; used after FMAs

            const float* __restrict__ Wd = &Wlds[dd * SLICE];

            float fn[KK];
#pragma unroll
            for (int j = 0; j < KK; ++j) fn[j] = f[0] * Wd[j];   // k=0 row: mul init
#pragma unroll
            for (int k = 1; k < KK; ++k) {
                const float fk = f[k];
#pragma unroll
                for (int j = 0; j < KK; ++j)
                    fn[j] = fmaf(fk, Wd[k * RS + j], fn[j]);
            }

            bernT(x, t);
            if (VAR) {
#pragma unroll
                for (int j = 0; j < KK; ++j) t[j] *= t[j];
            }
#pragma unroll
            for (int j = 0; j < KK; ++j) f[j] = fn[j] * t[j];
        }
    }

    float s = 0.0f;
#pragma unroll
    for (int j = 0; j < KK; ++j) s += f[j];
    if (VAR) s /= post_prec[p];

    atomicAdd(&out[(VAR ? NN : 0) + n], s);
}

// ---------- fallback (tiny workspace): round-2 proven path ----------
__device__ __forceinline__ void bern17(float x, float* b) {
    const float y = 1.0f - x;
    b[0] = 1.0f;
#pragma unroll
    for (int k = 1; k < KK; ++k) b[k] = b[k - 1] * x;
    float yp = 1.0f;
#pragma unroll
    for (int k = KK - 1; k >= 0; --k) {
        b[k] = b[k] * yp * binom16(k);
        yp *= y;
    }
}

__global__ void prep_var(const float* __restrict__ varw, const float* __restrict__ varw0,
                         const float* __restrict__ prior_sc,
                         float* __restrict__ wv, float* __restrict__ wv0) {
    const int E1 = (DD - 1) * PP * KK * KK;
    int idx = blockIdx.x * blockDim.x + threadIdx.x;
    if (idx < E1) {
        int j = idx % KK;
        float s = prior_sc[j];
        wv[idx] = expf(varw[idx]) * s * s;
    } else if (idx < E1 + PP * KK) {
        int i = idx - E1;
        int k = i % KK;
        float s = prior_sc[k];
        wv0[i] = expf(varw0[i]) * s * s;
    }
}

__global__ __launch_bounds__(256, 4) void bez_chain2(
    const float* __restrict__ Xb, const int sx_d, const int sx_n,
    const float* __restrict__ mw0, const float* __restrict__ mW,
    const float* __restrict__ vw0, const float* __restrict__ vW,
    const float* __restrict__ post_prec, const int* __restrict__ perm,
    float* __restrict__ out)
{
    const bool VAR = (blockIdx.z != 0);
    const int p = blockIdx.y;
    const int n = blockIdx.x * blockDim.x + threadIdx.x;
    const int* __restrict__ pp = perm + p * DD;
    const float* __restrict__ w0 = (VAR ? vw0 : mw0);
    const float* __restrict__ W  = (VAR ? vW  : mW);

    float f[KK], b[KK];
    {
        const int pd = pp[0];
        const float x = Xb[pd * sx_d + n * sx_n];
        bern17(x, b);
        if (VAR) {
#pragma unroll
            for (int k = 0; k < KK; ++k) b[k] *= b[k];
        }
        const float* __restrict__ w0p = w0 + p * KK;
#pragma unroll
        for (int k = 0; k < KK; ++k) f[k] = w0p[k] * b[k];
    }
    for (int d = 1; d < DD; ++d) {
        const int pd = pp[d];
        const float x = Xb[pd * sx_d + n * sx_n];
        bern17(x, b);
        if (VAR) {
#pragma unroll
            for (int k = 0; k < KK; ++k) b[k] *= b[k];
        }
        const float* __restrict__ Wd = W + ((size_t)(d - 1) * PP + p) * (KK * KK);
        float fn[KK];
#pragma unroll
        for (int j = 0; j < KK; ++j) fn[j] = 0.0f;
#pragma unroll
        for (int k = 0; k < KK; ++k) {
            const float fk = f[k];
#pragma unroll
            for (int j = 0; j < KK; ++j)
                fn[j] = fmaf(fk, Wd[k * KK + j], fn[j]);
        }
#pragma unroll
        for (int j = 0; j < KK; ++j) f[j] = fn[j] * b[j];
    }
    float s = 0.0f;
#pragma unroll
    for (int j = 0; j < KK; ++j) s += f[j];
    if (VAR) s /= post_prec[p];
    atomicAdd(&out[(VAR ? NN : 0) + n], s);
}
// --------------------------------------------------------------------

extern "C" void kernel_launch(void* const* d_in, const int* in_sizes, int n_in,
                              void* d_out, int out_size, void* d_ws, size_t ws_size,
                              hipStream_t stream) {
    const float* X    = (const float*)d_in[0];
    const float* mw0  = (const float*)d_in[1];
    const float* mw   = (const float*)d_in[2];
    const float* vw0  = (const float*)d_in[3];
    const float* vw   = (const float*)d_in[4];
    const float* psc  = (const float*)d_in[5];
    const float* ppr  = (const float*)d_in[6];
    const int*   perm = (const int*)d_in[7];
    float* out = (float*)d_out;

    hipMemsetAsync(d_out, 0, (size_t)out_size * sizeof(float), stream);

    const size_t xt_elems = (size_t)DD * NN;
    const size_t need_main = ((size_t)2 * WE + 2 * PP * KK + xt_elems) * sizeof(float);

    if (ws_size >= need_main) {
        float* Wm  = (float*)d_ws;             // [31,PP,17,20]
        float* Wv  = Wm + WE;
        float* w0m = Wv + WE;                  // [PP,17]
        float* w0v = w0m + PP * KK;
        float* XT  = w0v + PP * KK;            // [D,N]

        const int E = 2 * WE + 2 * PP * KK;
        prep_w<<<dim3((E + 255) / 256), dim3(256), 0, stream>>>(mw, vw, mw0, vw0, psc,
                                                                Wm, Wv, w0m, w0v);
        transpose_x<<<dim3(NN / 32), dim3(32, 8), 0, stream>>>(X, XT);

        dim3 grid(NN / 256, PP, 2), blk(256);
        bez_chainS<<<grid, blk, 0, stream>>>(XT, w0m, w0v, Wm, Wv, ppr, perm, out);
        return;
    }

    // Fallback: round-2 path.
    const size_t wv_elems  = (size_t)(DD - 1) * PP * KK * KK;
    const size_t wv0_elems = (size_t)PP * KK;
    float* wv_b  = (float*)d_ws;
    float* wv0_b = wv_b + wv_elems;
    float* XT    = wv0_b + wv0_elems;

    const int E = (DD - 1) * PP * KK * KK + PP * KK;
    prep_var<<<dim3((E + 255) / 256), dim3(256), 0, stream>>>(vw, vw0, psc, wv_b, wv0_b);

    const bool use_xt = ((wv_elems + wv0_elems + xt_elems) * sizeof(float) <= ws_size);
    const float* Xb = X;
    int sx_d = 1, sx_n = DD;
    if (use_xt) {
        transpose_x<<<dim3(NN / 32), dim3(32, 8), 0, stream>>>(X, XT);
        Xb = XT; sx_d = NN; sx_n = 1;
    }
    dim3 grid(NN / 256, PP, 2), blk(256);
    bez_chain2<<<grid, blk, 0, stream>>>(Xb, sx_d, sx_n, mw0, mw, wv0_b, wv_b, ppr, perm, out);
}

// Round 7
// 879.085 us; speedup vs baseline: 9.7274x; 9.7274x over previous
//
#include <hip/hip_runtime.h>

#define NN 24576
#define DD 32
#define KK 17
#define PP 20
#define WEU ((DD - 1) * PP * KK * KK)   // unpadded W elems per chain

__device__ __forceinline__ float binom16(int k) {
    const float b[KK] = {1.f, 16.f, 120.f, 560.f, 1820.f, 4368.f, 8008.f, 11440.f,
                         12870.f, 11440.f, 8008.f, 4368.f, 1820.f, 560.f, 120.f, 16.f, 1.f};
    return b[k];
}

// t[k] = x^k * (1-x)^(16-k)   (binom folded into weights by prep_w_fold)
__device__ __forceinline__ void bernT(float x, float* t) {
    const float y = 1.0f - x;
    t[0] = 1.0f;
#pragma unroll
    for (int k = 1; k < KK; ++k) t[k] = t[k - 1] * x;
    float yp = y;
#pragma unroll
    for (int k = KK - 2; k >= 0; --k) {
        t[k] *= yp;
        yp *= y;
    }
}

// Binom-folded, UNPADDED weight tables (stay on the s_load/SGPR path):
//  Wm2[d,p,k,j] = meanw[d,p,k,j] * binom[j]
//  Wv2[d,p,k,j] = exp(varw[d,p,k,j]) * (sc[j]*binom[j])^2
//  w0m[p,k] = meanw0[p,0,k] * binom[k];  w0v[p,k] = exp(varw0[p,0,k]) * (sc[k]*binom[k])^2
__global__ void prep_w_fold(const float* __restrict__ mw, const float* __restrict__ vw,
                            const float* __restrict__ mw0, const float* __restrict__ vw0,
                            const float* __restrict__ psc,
                            float* __restrict__ Wm2, float* __restrict__ Wv2,
                            float* __restrict__ w0m, float* __restrict__ w0v) {
    int idx = blockIdx.x * blockDim.x + threadIdx.x;
    if (idx < WEU) {
        const int j = idx % KK;
        Wm2[idx] = mw[idx] * binom16(j);
    } else if (idx < 2 * WEU) {
        const int i = idx - WEU;
        const int j = i % KK;
        const float s = psc[j] * binom16(j);
        Wv2[i] = expf(vw[i]) * s * s;
    } else if (idx < 2 * WEU + PP * KK) {
        const int i = idx - 2 * WEU;
        const int k = i % KK;
        w0m[i] = mw0[i] * binom16(k);
    } else if (idx < 2 * WEU + 2 * PP * KK) {
        const int i = idx - 2 * WEU - PP * KK;
        const int k = i % KK;
        const float s = psc[k] * binom16(k);
        w0v[i] = expf(vw0[i]) * s * s;
    }
}

// Transpose X [N,D] -> XT [D,N] so chain-kernel loads are lane-coalesced.
__global__ void transpose_x(const float* __restrict__ X, float* __restrict__ XT) {
    __shared__ float t[32][33];
    const int n0 = blockIdx.x * 32;
    for (int r = threadIdx.y; r < 32; r += 8)
        t[r][threadIdx.x] = X[(n0 + r) * DD + threadIdx.x];
    __syncthreads();
    for (int d = threadIdx.y; d < 32; d += 8)
        XT[d * NN + n0 + threadIdx.x] = t[threadIdx.x][d];
}

// FOUR n-points per thread, one chain per block (blockIdx.z). All four
// accumulator chains share ONE W s_load/SGPR stream; per 2-row s_load
// window there are now ~544cy of independent FMAs vs ~400cy latency ->
// per-wave self-covering. Plain scalar indexing = proven compact codegen
// (f[k] is consumed exactly once per row -> f/fn lifetimes cross over).
__global__ __launch_bounds__(256, 2) void bez_chain4x(
    const float* __restrict__ Xb,       // XT [DD,NN]
    const float* __restrict__ w0m,      // [PP,KK] folded
    const float* __restrict__ mW,       // [DD-1,PP,KK,KK] folded
    const float* __restrict__ w0v,      // [PP,KK] folded
    const float* __restrict__ vW,       // [DD-1,PP,KK,KK] folded
    const float* __restrict__ post_prec,// [PP]
    const int* __restrict__ perm,       // [PP,DD]
    float* __restrict__ out)            // [2*NN]
{
    const bool VAR = (blockIdx.z != 0);          // block-uniform branch
    const int p = blockIdx.y;
    const int n0 = blockIdx.x * 1024 + threadIdx.x;
    const int* __restrict__ pp = perm + p * DD;

    const float* __restrict__ w0 = (VAR ? w0v : w0m);
    const float* __restrict__ W  = (VAR ? vW  : mW);

    float f0[KK], f1[KK], f2[KK], f3[KK];

    {
        const int pd = pp[0];
        const float* __restrict__ xr = Xb + (size_t)pd * NN + n0;
        float b0[KK], b1[KK], b2[KK], b3[KK];
        bernT(xr[0], b0);
        bernT(xr[256], b1);
        bernT(xr[512], b2);
        bernT(xr[768], b3);
        if (VAR) {
#pragma unroll
            for (int k = 0; k < KK; ++k) {
                b0[k] *= b0[k]; b1[k] *= b1[k]; b2[k] *= b2[k]; b3[k] *= b3[k];
            }
        }
        const float* __restrict__ w0p = w0 + p * KK;
#pragma unroll
        for (int k = 0; k < KK; ++k) {
            const float w = w0p[k];
            f0[k] = w * b0[k]; f1[k] = w * b1[k]; f2[k] = w * b2[k]; f3[k] = w * b3[k];
        }
    }

    for (int d = 1; d < DD; ++d) {
        const int pd = pp[d];
        const float* __restrict__ xr = Xb + (size_t)pd * NN + n0;
        const float x0 = xr[0];
        const float x1 = xr[256];
        const float x2 = xr[512];
        const float x3 = xr[768];

        const float* __restrict__ Wd = W + ((size_t)(d - 1) * PP + p) * (KK * KK);

        float fn0[KK], fn1[KK], fn2[KK], fn3[KK];
#pragma unroll
        for (int j = 0; j < KK; ++j) {               // k=0 row: init with mul
            const float w = Wd[j];
            fn0[j] = f0[0] * w; fn1[j] = f1[0] * w;
            fn2[j] = f2[0] * w; fn3[j] = f3[0] * w;
        }
#pragma unroll
        for (int k = 1; k < KK; ++k) {
            const float a0 = f0[k], a1 = f1[k], a2 = f2[k], a3 = f3[k];
#pragma unroll
            for (int j = 0; j < KK; ++j) {
                const float w = Wd[k * KK + j];      // uniform -> ONE s_load stream
                fn0[j] = fmaf(a0, w, fn0[j]);
                fn1[j] = fmaf(a1, w, fn1[j]);
                fn2[j] = fmaf(a2, w, fn2[j]);
                fn3[j] = fmaf(a3, w, fn3[j]);
            }
        }

        float b0[KK], b1[KK], b2[KK], b3[KK];
        bernT(x0, b0);
        bernT(x1, b1);
        bernT(x2, b2);
        bernT(x3, b3);
        if (VAR) {
#pragma unroll
            for (int k = 0; k < KK; ++k) {
                b0[k] *= b0[k]; b1[k] *= b1[k]; b2[k] *= b2[k]; b3[k] *= b3[k];
            }
        }
#pragma unroll
        for (int j = 0; j < KK; ++j) {
            f0[j] = fn0[j] * b0[j]; f1[j] = fn1[j] * b1[j];
            f2[j] = fn2[j] * b2[j]; f3[j] = fn3[j] * b3[j];
        }
    }

    float s0 = 0.0f, s1 = 0.0f, s2 = 0.0f, s3 = 0.0f;
#pragma unroll
    for (int j = 0; j < KK; ++j) { s0 += f0[j]; s1 += f1[j]; s2 += f2[j]; s3 += f3[j]; }
    if (VAR) {
        const float ip = 1.0f / post_prec[p];
        s0 *= ip; s1 *= ip; s2 *= ip; s3 *= ip;
    }

    const int base = (VAR ? NN : 0) + n0;
    atomicAdd(&out[base], s0);
    atomicAdd(&out[base + 256], s1);
    atomicAdd(&out[base + 512], s2);
    atomicAdd(&out[base + 768], s3);
}

// ---------- fallback (tiny workspace): round-2 proven path ----------
__device__ __forceinline__ void bern17(float x, float* b) {
    const float y = 1.0f - x;
    b[0] = 1.0f;
#pragma unroll
    for (int k = 1; k < KK; ++k) b[k] = b[k - 1] * x;
    float yp = 1.0f;
#pragma unroll
    for (int k = KK - 1; k >= 0; --k) {
        b[k] = b[k] * yp * binom16(k);
        yp *= y;
    }
}

__global__ void prep_var(const float* __restrict__ varw, const float* __restrict__ varw0,
                         const float* __restrict__ prior_sc,
                         float* __restrict__ wv, float* __restrict__ wv0) {
    const int E1 = (DD - 1) * PP * KK * KK;
    int idx = blockIdx.x * blockDim.x + threadIdx.x;
    if (idx < E1) {
        int j = idx % KK;
        float s = prior_sc[j];
        wv[idx] = expf(varw[idx]) * s * s;
    } else if (idx < E1 + PP * KK) {
        int i = idx - E1;
        int k = i % KK;
        float s = prior_sc[k];
        wv0[i] = expf(varw0[i]) * s * s;
    }
}

__global__ __launch_bounds__(256, 4) void bez_chain2(
    const float* __restrict__ Xb, const int sx_d, const int sx_n,
    const float* __restrict__ mw0, const float* __restrict__ mW,
    const float* __restrict__ vw0, const float* __restrict__ vW,
    const float* __restrict__ post_prec, const int* __restrict__ perm,
    float* __restrict__ out)
{
    const bool VAR = (blockIdx.z != 0);
    const int p = blockIdx.y;
    const int n = blockIdx.x * blockDim.x + threadIdx.x;
    const int* __restrict__ pp = perm + p * DD;
    const float* __restrict__ w0 = (VAR ? vw0 : mw0);
    const float* __restrict__ W  = (VAR ? vW  : mW);

    float f[KK], b[KK];
    {
        const int pd = pp[0];
        const float x = Xb[pd * sx_d + n * sx_n];
        bern17(x, b);
        if (VAR) {
#pragma unroll
            for (int k = 0; k < KK; ++k) b[k] *= b[k];
        }
        const float* __restrict__ w0p = w0 + p * KK;
#pragma unroll
        for (int k = 0; k < KK; ++k) f[k] = w0p[k] * b[k];
    }
    for (int d = 1; d < DD; ++d) {
        const int pd = pp[d];
        const float x = Xb[pd * sx_d + n * sx_n];
        bern17(x, b);
        if (VAR) {
#pragma unroll
            for (int k = 0; k < KK; ++k) b[k] *= b[k];
        }
        const float* __restrict__ Wd = W + ((size_t)(d - 1) * PP + p) * (KK * KK);
        float fn[KK];
#pragma unroll
        for (int j = 0; j < KK; ++j) fn[j] = 0.0f;
#pragma unroll
        for (int k = 0; k < KK; ++k) {
            const float fk = f[k];
#pragma unroll
            for (int j = 0; j < KK; ++j)
                fn[j] = fmaf(fk, Wd[k * KK + j], fn[j]);
        }
#pragma unroll
        for (int j = 0; j < KK; ++j) f[j] = fn[j] * b[j];
    }
    float s = 0.0f;
#pragma unroll
    for (int j = 0; j < KK; ++j) s += f[j];
    if (VAR) s /= post_prec[p];
    atomicAdd(&out[(VAR ? NN : 0) + n], s);
}
// --------------------------------------------------------------------

extern "C" void kernel_launch(void* const* d_in, const int* in_sizes, int n_in,
                              void* d_out, int out_size, void* d_ws, size_t ws_size,
                              hipStream_t stream) {
    const float* X    = (const float*)d_in[0];
    const float* mw0  = (const float*)d_in[1];
    const float* mw   = (const float*)d_in[2];
    const float* vw0  = (const float*)d_in[3];
    const float* vw   = (const float*)d_in[4];
    const float* psc  = (const float*)d_in[5];
    const float* ppr  = (const float*)d_in[6];
    const int*   perm = (const int*)d_in[7];
    float* out = (float*)d_out;

    hipMemsetAsync(d_out, 0, (size_t)out_size * sizeof(float), stream);

    const size_t xt_elems = (size_t)DD * NN;
    const size_t need_main = ((size_t)2 * WEU + 2 * PP * KK + xt_elems) * sizeof(float);

    if (ws_size >= need_main) {
        float* Wm2 = (float*)d_ws;             // [31,PP,17,17] folded
        float* Wv2 = Wm2 + WEU;
        float* w0m = Wv2 + WEU;                // [PP,17]
        float* w0v = w0m + PP * KK;
        float* XT  = w0v + PP * KK;            // [D,N]

        const int E = 2 * WEU + 2 * PP * KK;
        prep_w_fold<<<dim3((E + 255) / 256), dim3(256), 0, stream>>>(mw, vw, mw0, vw0, psc,
                                                                     Wm2, Wv2, w0m, w0v);
        transpose_x<<<dim3(NN / 32), dim3(32, 8), 0, stream>>>(X, XT);

        dim3 grid(NN / 1024, PP, 2), blk(256);
        bez_chain4x<<<grid, blk, 0, stream>>>(XT, w0m, Wm2, w0v, Wv2, ppr, perm, out);
        return;
    }

    // Fallback: round-2 path.
    const size_t wv_elems  = (size_t)(DD - 1) * PP * KK * KK;
    const size_t wv0_elems = (size_t)PP * KK;
    float* wv_b  = (float*)d_ws;
    float* wv0_b = wv_b + wv_elems;
    float* XT    = wv0_b + wv0_elems;

    const int E = (DD - 1) * PP * KK * KK + PP * KK;
    prep_var<<<dim3((E + 255) / 256), dim3(256), 0, stream>>>(vw, vw0, psc, wv_b, wv0_b);

    const bool use_xt = ((wv_elems + wv0_elems + xt_elems) * sizeof(float) <= ws_size);
    const float* Xb = X;
    int sx_d = 1, sx_n = DD;
    if (use_xt) {
        transpose_x<<<dim3(NN / 32), dim3(32, 8), 0, stream>>>(X, XT);
        Xb = XT; sx_d = NN; sx_n = 1;
    }
    dim3 grid(NN / 256, PP, 2), blk(256);
    bez_chain2<<<grid, blk, 0, stream>>>(Xb, sx_d, sx_n, mw0, mw, wv0_b, wv_b, ppr, perm, out);
}

// Round 8
// 821.362 us; speedup vs baseline: 10.4110x; 1.0703x over previous
//
#include <hip/hip_runtime.h>

#define NN 24576
#define DD 32
#define KK 17
#define PP 20
#define RS 20                       // padded W row stride (floats), 80 B -> 16B-aligned rows
#define SLICE (KK * RS)             // 340 floats per (d,p) slice (1360 B, fits 13-bit imm)
#define WE ((DD - 1) * PP * SLICE)  // padded W elems per chain

__device__ __forceinline__ float binom16(int k) {
    const float b[KK] = {1.f, 16.f, 120.f, 560.f, 1820.f, 4368.f, 8008.f, 11440.f,
                         12870.f, 11440.f, 8008.f, 4368.f, 1820.f, 560.f, 120.f, 16.f, 1.f};
    return b[k];
}

// t[k] = x^k * (1-x)^(16-k)   (binom folded into weights by prep_w)
__device__ __forceinline__ void bernT(float x, float* t) {
    const float y = 1.0f - x;
    t[0] = 1.0f;
#pragma unroll
    for (int k = 1; k < KK; ++k) t[k] = t[k - 1] * x;
    float yp = y;
#pragma unroll
    for (int k = KK - 2; k >= 0; --k) {
        t[k] *= yp;
        yp *= y;
    }
}

// Padded (RS=20), binom-folded weight tables (proven correct in R4/R6):
//  Wm[d,p,k,j20] = meanw[d,p,k,j] * binom[j]
//  Wv[d,p,k,j20] = exp(varw[d,p,k,j]) * (sc[j]*binom[j])^2
//  w0m[p,k] = meanw0[p,0,k]*binom[k];  w0v[p,k] = exp(varw0[p,0,k])*(sc[k]*binom[k])^2
__global__ void prep_w(const float* __restrict__ mw, const float* __restrict__ vw,
                       const float* __restrict__ mw0, const float* __restrict__ vw0,
                       const float* __restrict__ psc,
                       float* __restrict__ Wm, float* __restrict__ Wv,
                       float* __restrict__ w0m, float* __restrict__ w0v) {
    int idx = blockIdx.x * blockDim.x + threadIdx.x;
    if (idx < WE) {
        const int j = idx % RS;
        const int k = (idx / RS) % KK;
        const int p = (idx / SLICE) % PP;
        const int dm1 = idx / (SLICE * PP);
        float v = 0.0f;
        if (j < KK)
            v = mw[(((size_t)dm1 * PP + p) * KK + k) * KK + j] * binom16(j);
        Wm[idx] = v;
    } else if (idx < 2 * WE) {
        const int i = idx - WE;
        const int j = i % RS;
        const int k = (i / RS) % KK;
        const int p = (i / SLICE) % PP;
        const int dm1 = i / (SLICE * PP);
        float v = 0.0f;
        if (j < KK) {
            const float s = psc[j] * binom16(j);
            v = expf(vw[(((size_t)dm1 * PP + p) * KK + k) * KK + j]) * s * s;
        }
        Wv[i] = v;
    } else if (idx < 2 * WE + PP * KK) {
        const int i = idx - 2 * WE;
        const int k = i % KK;
        w0m[i] = mw0[i] * binom16(k);
    } else if (idx < 2 * WE + 2 * PP * KK) {
        const int i = idx - 2 * WE - PP * KK;
        const int k = i % KK;
        const float s = psc[k] * binom16(k);
        w0v[i] = expf(vw0[i]) * s * s;
    }
}

// Transpose X [N,D] -> XT [D,N] so chain-kernel loads are lane-coalesced.
__global__ void transpose_x(const float* __restrict__ X, float* __restrict__ XT) {
    __shared__ float t[32][33];
    const int n0 = blockIdx.x * 32;
    for (int r = threadIdx.y; r < 32; r += 8)
        t[r][threadIdx.x] = X[(n0 + r) * DD + threadIdx.x];
    __syncthreads();
    for (int d = threadIdx.y; d < 32; d += 8)
        XT[d * NN + n0 + threadIdx.x] = t[threadIdx.x][d];
}

// R5's proven 2pt body, with ONE change: W is read through a pointer with an
// opaque (asm) zero added, so uniformity can't be proven -> compiler emits
// VECTOR global_load (all lanes same addr = single broadcast request) instead
// of s_load. VMEM pipelines dozens-deep under vmcnt (vs ~4 rows under SGPR
// pressure) and sibling waves hit vector L1. Rows padded to 80 B so
// j-consecutive loads merge into aligned dwordx4.
__global__ __launch_bounds__(256, 4) void bez_chainV(
    const float* __restrict__ Xb,       // XT [DD,NN]
    const float* __restrict__ w0m,      // [PP,KK] folded
    const float* __restrict__ mW,       // [DD-1,PP,17,20] folded, padded
    const float* __restrict__ w0v,      // [PP,KK] folded
    const float* __restrict__ vW,       // [DD-1,PP,17,20] folded, padded
    const float* __restrict__ post_prec,// [PP]
    const int* __restrict__ perm,       // [PP,DD]
    float* __restrict__ out)            // [2*NN]
{
    const bool VAR = (blockIdx.z != 0);          // block-uniform branch
    const int p = blockIdx.y;
    const int n0 = blockIdx.x * 512 + threadIdx.x;
    const int n1 = n0 + 256;
    const int* __restrict__ pp = perm + p * DD;

    // opaque zero: defeats uniformity analysis for W addressing only
    int vzero;
    asm volatile("v_mov_b32 %0, 0" : "=v"(vzero));

    const float* __restrict__ w0 = (VAR ? w0v : w0m);
    const float* __restrict__ W  = (VAR ? vW  : mW) + vzero;

    float f0[KK], f1[KK], b0[KK], b1[KK];

    {
        const int pd = pp[0];
        bernT(Xb[pd * NN + n0], b0);
        bernT(Xb[pd * NN + n1], b1);
        if (VAR) {
#pragma unroll
            for (int k = 0; k < KK; ++k) { b0[k] *= b0[k]; b1[k] *= b1[k]; }
        }
        const float* __restrict__ w0p = w0 + p * KK;
#pragma unroll
        for (int k = 0; k < KK; ++k) { f0[k] = w0p[k] * b0[k]; f1[k] = w0p[k] * b1[k]; }
    }

    for (int d = 1; d < DD; ++d) {
        const int pd = pp[d];
        const float x0 = Xb[pd * NN + n0];
        const float x1 = Xb[pd * NN + n1];

        const float* __restrict__ Wd = W + ((size_t)(d - 1) * PP + p) * SLICE;

        float fn0[KK], fn1[KK];
#pragma unroll
        for (int j = 0; j < KK; ++j) {               // k=0 row: init with mul
            const float w = Wd[j];
            fn0[j] = f0[0] * w;
            fn1[j] = f1[0] * w;
        }
#pragma unroll
        for (int k = 1; k < KK; ++k) {
            const float fk0 = f0[k];
            const float fk1 = f1[k];
#pragma unroll
            for (int j = 0; j < KK; ++j) {
                const float w = Wd[k * RS + j];      // vector broadcast load, ONE stream
                fn0[j] = fmaf(fk0, w, fn0[j]);
                fn1[j] = fmaf(fk1, w, fn1[j]);
            }
        }

        bernT(x0, b0);
        bernT(x1, b1);
        if (VAR) {
#pragma unroll
            for (int k = 0; k < KK; ++k) { b0[k] *= b0[k]; b1[k] *= b1[k]; }
        }
#pragma unroll
        for (int j = 0; j < KK; ++j) { f0[j] = fn0[j] * b0[j]; f1[j] = fn1[j] * b1[j]; }
    }

    float s0 = 0.0f, s1 = 0.0f;
#pragma unroll
    for (int j = 0; j < KK; ++j) { s0 += f0[j]; s1 += f1[j]; }
    if (VAR) { const float ip = 1.0f / post_prec[p]; s0 *= ip; s1 *= ip; }

    const int base = (VAR ? NN : 0);
    atomicAdd(&out[base + n0], s0);
    atomicAdd(&out[base + n1], s1);
}

// ---------- fallback (tiny workspace): round-2 proven path ----------
__device__ __forceinline__ void bern17(float x, float* b) {
    const float y = 1.0f - x;
    b[0] = 1.0f;
#pragma unroll
    for (int k = 1; k < KK; ++k) b[k] = b[k - 1] * x;
    float yp = 1.0f;
#pragma unroll
    for (int k = KK - 1; k >= 0; --k) {
        b[k] = b[k] * yp * binom16(k);
        yp *= y;
    }
}

__global__ void prep_var(const float* __restrict__ varw, const float* __restrict__ varw0,
                         const float* __restrict__ prior_sc,
                         float* __restrict__ wv, float* __restrict__ wv0) {
    const int E1 = (DD - 1) * PP * KK * KK;
    int idx = blockIdx.x * blockDim.x + threadIdx.x;
    if (idx < E1) {
        int j = idx % KK;
        float s = prior_sc[j];
        wv[idx] = expf(varw[idx]) * s * s;
    } else if (idx < E1 + PP * KK) {
        int i = idx - E1;
        int k = i % KK;
        float s = prior_sc[k];
        wv0[i] = expf(varw0[i]) * s * s;
    }
}

__global__ __launch_bounds__(256, 4) void bez_chain2(
    const float* __restrict__ Xb, const int sx_d, const int sx_n,
    const float* __restrict__ mw0, const float* __restrict__ mW,
    const float* __restrict__ vw0, const float* __restrict__ vW,
    const float* __restrict__ post_prec, const int* __restrict__ perm,
    float* __restrict__ out)
{
    const bool VAR = (blockIdx.z != 0);
    const int p = blockIdx.y;
    const int n = blockIdx.x * blockDim.x + threadIdx.x;
    const int* __restrict__ pp = perm + p * DD;
    const float* __restrict__ w0 = (VAR ? vw0 : mw0);
    const float* __restrict__ W  = (VAR ? vW  : mW);

    float f[KK], b[KK];
    {
        const int pd = pp[0];
        const float x = Xb[pd * sx_d + n * sx_n];
        bern17(x, b);
        if (VAR) {
#pragma unroll
            for (int k = 0; k < KK; ++k) b[k] *= b[k];
        }
        const float* __restrict__ w0p = w0 + p * KK;
#pragma unroll
        for (int k = 0; k < KK; ++k) f[k] = w0p[k] * b[k];
    }
    for (int d = 1; d < DD; ++d) {
        const int pd = pp[d];
        const float x = Xb[pd * sx_d + n * sx_n];
        bern17(x, b);
        if (VAR) {
#pragma unroll
            for (int k = 0; k < KK; ++k) b[k] *= b[k];
        }
        const float* __restrict__ Wd = W + ((size_t)(d - 1) * PP + p) * (KK * KK);
        float fn[KK];
#pragma unroll
        for (int j = 0; j < KK; ++j) fn[j] = 0.0f;
#pragma unroll
        for (int k = 0; k < KK; ++k) {
            const float fk = f[k];
#pragma unroll
            for (int j = 0; j < KK; ++j)
                fn[j] = fmaf(fk, Wd[k * KK + j], fn[j]);
        }
#pragma unroll
        for (int j = 0; j < KK; ++j) f[j] = fn[j] * b[j];
    }
    float s = 0.0f;
#pragma unroll
    for (int j = 0; j < KK; ++j) s += f[j];
    if (VAR) s /= post_prec[p];
    atomicAdd(&out[(VAR ? NN : 0) + n], s);
}
// --------------------------------------------------------------------

extern "C" void kernel_launch(void* const* d_in, const int* in_sizes, int n_in,
                              void* d_out, int out_size, void* d_ws, size_t ws_size,
                              hipStream_t stream) {
    const float* X    = (const float*)d_in[0];
    const float* mw0  = (const float*)d_in[1];
    const float* mw   = (const float*)d_in[2];
    const float* vw0  = (const float*)d_in[3];
    const float* vw   = (const float*)d_in[4];
    const float* psc  = (const float*)d_in[5];
    const float* ppr  = (const float*)d_in[6];
    const int*   perm = (const int*)d_in[7];
    float* out = (float*)d_out;

    hipMemsetAsync(d_out, 0, (size_t)out_size * sizeof(float), stream);

    const size_t xt_elems = (size_t)DD * NN;
    const size_t need_main = ((size_t)2 * WE + 2 * PP * KK + xt_elems) * sizeof(float);

    if (ws_size >= need_main) {
        float* Wm  = (float*)d_ws;             // [31,PP,17,20] folded
        float* Wv  = Wm + WE;
        float* w0m = Wv + WE;                  // [PP,17]
        float* w0v = w0m + PP * KK;
        float* XT  = w0v + PP * KK;            // [D,N]

        const int E = 2 * WE + 2 * PP * KK;
        prep_w<<<dim3((E + 255) / 256), dim3(256), 0, stream>>>(mw, vw, mw0, vw0, psc,
                                                                Wm, Wv, w0m, w0v);
        transpose_x<<<dim3(NN / 32), dim3(32, 8), 0, stream>>>(X, XT);

        dim3 grid(NN / 512, PP, 2), blk(256);
        bez_chainV<<<grid, blk, 0, stream>>>(XT, w0m, Wm, w0v, Wv, ppr, perm, out);
        return;
    }

    // Fallback: round-2 path.
    const size_t wv_elems  = (size_t)(DD - 1) * PP * KK * KK;
    const size_t wv0_elems = (size_t)PP * KK;
    float* wv_b  = (float*)d_ws;
    float* wv0_b = wv_b + wv_elems;
    float* XT    = wv0_b + wv0_elems;

    const int E = (DD - 1) * PP * KK * KK + PP * KK;
    prep_var<<<dim3((E + 255) / 256), dim3(256), 0, stream>>>(vw, vw0, psc, wv_b, wv0_b);

    const bool use_xt = ((wv_elems + wv0_elems + xt_elems) * sizeof(float) <= ws_size);
    const float* Xb = X;
    int sx_d = 1, sx_n = DD;
    if (use_xt) {
        transpose_x<<<dim3(NN / 32), dim3(32, 8), 0, stream>>>(X, XT);
        Xb = XT; sx_d = NN; sx_n = 1;
    }
    dim3 grid(NN / 256, PP, 2), blk(256);
    bez_chain2<<<grid, blk, 0, stream>>>(Xb, sx_d, sx_n, mw0, mw, wv0_b, wv_b, ppr, perm, out);
}